// Round 19
// baseline (385.349 us; speedup 1.0000x reference)
//
#include <hip/hip_runtime.h>
#include <hip/hip_bf16.h>

#define B_ 4
#define S_ 4096
#define D_ 768
#define H_ 12
#define DH_ 64
#define G_ 64
#define C_ 256
#define FF_ 3072

typedef __attribute__((ext_vector_type(8))) short bf16x8;
typedef __attribute__((ext_vector_type(4))) float f32x4;
typedef unsigned short u16;

__device__ __forceinline__ float bfu2f(u16 u) {
    return __uint_as_float((unsigned)u << 16);
}

// ---------------------------------------------------------------------------
// async global->LDS 16B (wave-uniform LDS base + lane*16)
// ---------------------------------------------------------------------------
__device__ __forceinline__ void gload16(const __hip_bfloat16* g, __hip_bfloat16* l) {
    __builtin_amdgcn_global_load_lds(
        (__attribute__((address_space(1))) void*)(void*)const_cast<__hip_bfloat16*>(g),
        (__attribute__((address_space(3))) void*)(void*)l,
        16, 0, 0);
}

// ---------------------------------------------------------------------------
// gemm256 — 8-phase schedule (r10 verbatim): 256x256 tile, BK=64, 8 waves.
// A: MxK bf16, Bt: NxK bf16. Out bf16. flags: 1=bias, 2=relu.
// M%256==0, N%256==0, K%128==0, nwg%8==0.
// ---------------------------------------------------------------------------
__global__ __launch_bounds__(512, 2) void gemm256(
    const u16* __restrict__ A, const u16* __restrict__ Bt,
    const float* __restrict__ bias, u16* __restrict__ Cb,
    int M, int N, int K, int flags)
{
    __shared__ __attribute__((aligned(16))) u16 Ah[2][2][128 * 64];
    __shared__ __attribute__((aligned(16))) u16 Bh[2][2][128 * 64];

    const int tid = threadIdx.x;
    const int lane = tid & 63, w = tid >> 6;
    const int wm = w >> 2, wn = w & 3;
    const int r = lane & 15, qd = lane >> 4;

    int lin = blockIdx.y * gridDim.x + blockIdx.x;
    int nwg = gridDim.x * gridDim.y;
    int cpx = nwg >> 3;
    int swz = (lin & 7) * cpx + (lin >> 3);
    int bm = (swz / gridDim.x) * 256;
    int bn = (swz % gridDim.x) * 256;

    const int srow = tid >> 3;
    const int scol = ((tid & 7) ^ (srow & 7)) * 8;
    const int sdst = tid * 8;

#define STG_A(c, h, kt) { \
    const u16* s_ = A + (size_t)(bm + (h) * 128 + srow) * K + ((kt) << 6) + scol; \
    gload16((const __hip_bfloat16*)s_, (__hip_bfloat16*)&Ah[c][h][sdst]); \
    gload16((const __hip_bfloat16*)(s_ + (size_t)64 * K), (__hip_bfloat16*)&Ah[c][h][sdst + 4096]); }
#define STG_B(c, h, kt) { \
    const u16* s_ = Bt + (size_t)(bn + (h) * 128 + srow) * K + ((kt) << 6) + scol; \
    gload16((const __hip_bfloat16*)s_, (__hip_bfloat16*)&Bh[c][h][sdst]); \
    gload16((const __hip_bfloat16*)(s_ + (size_t)64 * K), (__hip_bfloat16*)&Bh[c][h][sdst + 4096]); }

#define GRAN(kk) (((((kk) << 2) + qd) ^ (r & 7)) * 8)
#define READS_AF(c, mb) { \
    _Pragma("unroll") for (int m = 0; m < 4; ++m) { \
        const u16* p_ = &Ah[c][wm][((mb + m) * 16 + r) * 64]; \
        af[m][0] = *(const bf16x8*)(p_ + GRAN(0)); \
        af[m][1] = *(const bf16x8*)(p_ + GRAN(1)); } }
#define READS_BF(dst, c, nb) { \
    _Pragma("unroll") for (int n = 0; n < 2; ++n) { \
        const u16* p_ = &Bh[c][wn >> 1][((wn & 1) * 64 + (nb + n) * 16 + r) * 64]; \
        dst[n][0] = *(const bf16x8*)(p_ + GRAN(0)); \
        dst[n][1] = *(const bf16x8*)(p_ + GRAN(1)); } }
#define QMFMA(mb, nb, bfx) { \
    __builtin_amdgcn_s_setprio(1); \
    _Pragma("unroll") for (int kk = 0; kk < 2; ++kk) \
    _Pragma("unroll") for (int m = 0; m < 4; ++m) \
    _Pragma("unroll") for (int n = 0; n < 2; ++n) \
        acc[mb + m][nb + n] = __builtin_amdgcn_mfma_f32_16x16x32_bf16( \
            af[m][kk], bfx[n][kk], acc[mb + m][nb + n], 0, 0, 0); \
    __builtin_amdgcn_s_setprio(0); }
#define BAR() __builtin_amdgcn_s_barrier()
#define LGKM0() asm volatile("s_waitcnt lgkmcnt(0)" ::: "memory")

    f32x4 acc[8][4] = {};
    const int NT = K >> 6;
    const int J = NT >> 1;

    bf16x8 af[4][2], bfa[2][2], bfb[2][2];

    STG_A(0, 0, 0) STG_A(0, 1, 0) STG_B(0, 0, 0) STG_B(0, 1, 0)
    STG_A(1, 0, 1) STG_A(1, 1, 1)
    asm volatile("s_waitcnt vmcnt(4)" ::: "memory");
    BAR();
    READS_AF(0, 0) READS_BF(bfa, 0, 0)

    for (int j = 0; j < J; ++j) {
        const int to1 = 2 * j + 1, te2 = 2 * j + 2, to3 = 2 * j + 3;
        const bool pf = (j + 1 < J);

        STG_B(1, 0, to1)
        BAR(); LGKM0();
        QMFMA(0, 0, bfa)
        READS_BF(bfb, 0, 2)
        BAR();
        STG_B(1, 1, to1)
        BAR(); LGKM0();
        QMFMA(0, 2, bfb)
        READS_AF(0, 4)
        BAR();
        LGKM0();
        QMFMA(4, 2, bfb)
        BAR();
        if (pf) { STG_A(0, 0, te2) STG_A(0, 1, te2) }
        BAR();
        QMFMA(4, 0, bfa)
        if (pf) asm volatile("s_waitcnt vmcnt(4)" ::: "memory");
        else    asm volatile("s_waitcnt vmcnt(0)" ::: "memory");
        BAR();
        READS_AF(1, 0) READS_BF(bfa, 1, 0)
        if (pf) { STG_B(0, 0, te2) }
        BAR(); LGKM0();
        QMFMA(0, 0, bfa)
        READS_BF(bfb, 1, 2)
        BAR();
        if (pf) { STG_B(0, 1, te2) }
        BAR(); LGKM0();
        QMFMA(0, 2, bfb)
        READS_AF(1, 4)
        BAR();
        LGKM0();
        QMFMA(4, 2, bfb)
        BAR();
        if (pf) { STG_A(1, 0, to3) STG_A(1, 1, to3) }
        BAR();
        QMFMA(4, 0, bfa)
        if (pf) {
            asm volatile("s_waitcnt vmcnt(4)" ::: "memory");
            BAR();
            READS_AF(0, 0) READS_BF(bfa, 0, 0)
        }
    }

#pragma unroll
    for (int m = 0; m < 8; ++m) {
        int row0 = bm + wm * 128 + m * 16 + qd * 4;
#pragma unroll
        for (int n = 0; n < 4; ++n) {
            int col = bn + wn * 64 + n * 16 + r;
            float bv = (flags & 1) ? bias[col] : 0.0f;
#pragma unroll
            for (int i = 0; i < 4; ++i) {
                float v = acc[m][n][i] + bv;
                if (flags & 2) v = fmaxf(v, 0.0f);
                __hip_bfloat16 ob = __float2bfloat16(v);
                Cb[(size_t)(row0 + i) * N + col] = *(u16*)&ob;
            }
        }
    }
#undef STG_A
#undef STG_B
#undef GRAN
#undef READS_AF
#undef READS_BF
#undef QMFMA
#undef BAR
#undef LGKM0
}

// ---------------------------------------------------------------------------
// gemm128 body — 128x128, BK=64, 8 waves; single-barrier stage-first 2-phase.
// ---------------------------------------------------------------------------
__device__ __forceinline__ void gemm128_body(
    const u16* __restrict__ A, const u16* __restrict__ Bt,
    const float* __restrict__ bias, u16* __restrict__ Cb,
    int M, int N, int K, int flags, int bm, int bn)
{
    __shared__ __attribute__((aligned(16))) u16 As[2][128 * 64];
    __shared__ __attribute__((aligned(16))) u16 Bs[2][128 * 64];

    const int tid = threadIdx.x;
    const int lane = tid & 63, w = tid >> 6;
    const int wm = w >> 2, wn = w & 3;
    const int r = lane & 15, qd = lane >> 4;

    const int srow = tid >> 3;
    const int sg = ((tid & 7) ^ (srow & 7)) * 8;

#define STG(c, kt) { \
    const u16* a_ = A + (size_t)(bm + srow) * K + ((kt) << 6) + sg; \
    gload16((const __hip_bfloat16*)a_, (__hip_bfloat16*)&As[c][tid * 8]); \
    gload16((const __hip_bfloat16*)(a_ + (size_t)64 * K), (__hip_bfloat16*)&As[c][4096 + tid * 8]); \
    const u16* b_ = Bt + (size_t)(bn + srow) * K + ((kt) << 6) + sg; \
    gload16((const __hip_bfloat16*)b_, (__hip_bfloat16*)&Bs[c][tid * 8]); \
    gload16((const __hip_bfloat16*)(b_ + (size_t)64 * K), (__hip_bfloat16*)&Bs[c][4096 + tid * 8]); }

#define GR(kk) (((((kk) << 2) + qd) ^ (r & 7)) * 8)

    f32x4 acc[4][2] = {};
    const int NT = K >> 6;

    STG(0, 0)
    asm volatile("s_waitcnt vmcnt(0)" ::: "memory");
    __builtin_amdgcn_s_barrier();

    for (int kt = 0; kt < NT; ++kt) {
        const int c = kt & 1;
        if (kt + 1 < NT) STG(c ^ 1, kt + 1)
        const u16* as = As[c];
        const u16* bs = Bs[c];
#pragma unroll
        for (int kk = 0; kk < 2; ++kk) {
            bf16x8 af[4], bf[2];
#pragma unroll
            for (int m = 0; m < 4; ++m)
                af[m] = *(const bf16x8*)&as[(wm * 64 + m * 16 + r) * 64 + GR(kk)];
#pragma unroll
            for (int n = 0; n < 2; ++n)
                bf[n] = *(const bf16x8*)&bs[(wn * 32 + n * 16 + r) * 64 + GR(kk)];
            __builtin_amdgcn_s_setprio(1);
#pragma unroll
            for (int m = 0; m < 4; ++m)
#pragma unroll
                for (int n = 0; n < 2; ++n)
                    acc[m][n] = __builtin_amdgcn_mfma_f32_16x16x32_bf16(
                        af[m], bf[n], acc[m][n], 0, 0, 0);
            __builtin_amdgcn_s_setprio(0);
        }
        asm volatile("s_waitcnt vmcnt(0)" ::: "memory");
        __builtin_amdgcn_s_barrier();
    }

#pragma unroll
    for (int m = 0; m < 4; ++m) {
        int row0 = bm + wm * 64 + m * 16 + qd * 4;
#pragma unroll
        for (int n = 0; n < 2; ++n) {
            int col = bn + wn * 32 + n * 16 + r;
            float bv = (flags & 1) ? bias[col] : 0.0f;
#pragma unroll
            for (int i = 0; i < 4; ++i) {
                float v = acc[m][n][i] + bv;
                if (flags & 2) v = fmaxf(v, 0.0f);
                __hip_bfloat16 ob = __float2bfloat16(v);
                Cb[(size_t)(row0 + i) * N + col] = *(u16*)&ob;
            }
        }
    }
#undef STG
#undef GR
}

// plain gemm128 (oproj): own XCD swizzle
__global__ __launch_bounds__(512, 4) void gemm128(
    const u16* __restrict__ A, const u16* __restrict__ Bt,
    const float* __restrict__ bias, u16* __restrict__ Cb,
    int M, int N, int K, int flags)
{
    int lin = blockIdx.y * gridDim.x + blockIdx.x;
    int nwg = gridDim.x * gridDim.y;
    int cpx = nwg >> 3;
    int swz = (lin & 7) * cpx + (lin >> 3);
    int bm = (swz / gridDim.x) * 128;
    int bn = (swz % gridDim.x) * 128;
    gemm128_body(A, Bt, bias, Cb, M, N, K, flags, bm, bn);
}

// fused q-proj + kv-proj in ONE dispatch (816 blocks; 816 % 8 == 0).
__global__ __launch_bounds__(512, 4) void gemm128_qkv(
    const u16* __restrict__ curb, const u16* __restrict__ Wqt,
    const float* __restrict__ bq, u16* __restrict__ qout,
    const u16* __restrict__ Pselb, const u16* __restrict__ Wkvt,
    const float* __restrict__ bkv, u16* __restrict__ kvout)
{
    int lin = blockIdx.x;
    int nwg = gridDim.x;                 // 816
    int cpx = nwg >> 3;
    int swz = (lin & 7) * cpx + (lin >> 3);
    if (swz < 768) {
        int bm = (swz / 6) * 128, bn = (swz % 6) * 128;
        gemm128_body(curb, Wqt, bq, qout, B_ * S_, D_, D_, 1, bm, bn);
    } else {
        int s2 = swz - 768;
        int bm = (s2 / 12) * 128, bn = (s2 % 12) * 128;
        gemm128_body(Pselb, Wkvt, bkv, kvout, B_ * 128, 2 * D_, D_, 1, bm, bn);
    }
}

// ---------------------------------------------------------------------------
// preamble — ALL independent prep work in ONE dispatch (block-range routed)
// ---------------------------------------------------------------------------
#define PRE_NBLK 13658

__global__ __launch_bounds__(256) void preamble(
    const float* __restrict__ cur, const float* __restrict__ prev,
    const int* __restrict__ ridx,
    const float* __restrict__ Wq, const float* __restrict__ Wo,
    const float* __restrict__ Wk, const float* __restrict__ Wv,
    const float* __restrict__ W1, const float* __restrict__ W2,
    const float* __restrict__ Wqc, const float* __restrict__ Wkc,
    const float* __restrict__ bqc, const float* __restrict__ Wvc,
    const float* __restrict__ Woc, const float* __restrict__ bvc,
    const float* __restrict__ boc, const float* __restrict__ bk,
    const float* __restrict__ bv,
    __hip_bfloat16* __restrict__ Pselb, int* __restrict__ sel,
    __hip_bfloat16* __restrict__ curb,
    __hip_bfloat16* __restrict__ Wqt, __hip_bfloat16* __restrict__ Wot,
    __hip_bfloat16* __restrict__ Wkt, __hip_bfloat16* __restrict__ Wvt,
    __hip_bfloat16* __restrict__ W1t, __hip_bfloat16* __restrict__ W2t,
    float* __restrict__ Ut, float* __restrict__ ab,
    float* __restrict__ Wmix, float* __restrict__ bias2,
    float* __restrict__ bkv)
{
    int blk = blockIdx.x;
    if (blk < 6912) {
        int tile = blk;
        const float* W; __hip_bfloat16* Wt; int K, N;
        if (tile < 2304) {
            int w = tile / 576; tile -= w * 576;
            K = 768; N = 768;
            W  = (w == 0) ? Wq : (w == 1) ? Wo : (w == 2) ? Wk : Wv;
            Wt = (w == 0) ? Wqt : (w == 1) ? Wot : (w == 2) ? Wkt : Wvt;
        } else if (tile < 4608) { tile -= 2304; K = 768; N = 3072; W = W1; Wt = W1t; }
        else                    { tile -= 4608; K = 3072; N = 768; W = W2; Wt = W2t; }
        int ntx = N >> 5;
        int k0 = (tile / ntx) * 32, n0 = (tile % ntx) * 32;
        __shared__ float s[32][33];
        int tx = threadIdx.x & 31, ty = threadIdx.x >> 5;
#pragma unroll
        for (int i = 0; i < 4; ++i)
            s[ty + i * 8][tx] = W[(size_t)(k0 + ty + i * 8) * N + n0 + tx];
        __syncthreads();
#pragma unroll
        for (int i = 0; i < 4; ++i)
            Wt[(size_t)(n0 + ty + i * 8) * K + k0 + tx] =
                __float2bfloat16(s[tx][ty + i * 8]);
    } else if (blk < 13056) {
        int i = (blk - 6912) * 256 + threadIdx.x;
        const float4* p = (const float4*)(cur + (size_t)i * 8);
        float4 v0 = p[0], v1 = p[1];
        __hip_bfloat16 o[8] = {
            __float2bfloat16(v0.x), __float2bfloat16(v0.y),
            __float2bfloat16(v0.z), __float2bfloat16(v0.w),
            __float2bfloat16(v1.x), __float2bfloat16(v1.y),
            __float2bfloat16(v1.z), __float2bfloat16(v1.w)};
        *(uint4*)(curb + (size_t)i * 8) = *(const uint4*)o;
    } else if (blk < 13568) {
        int j = blk - 13056;
        int b = j >> 7, i = j & 127;
        int sv = (i < 64) ? i : ridx[b * G_ + (i - 64)];
        if (threadIdx.x == 0) sel[j] = sv;
        const float* src = prev + ((size_t)(b * S_ + sv)) * D_;
        __hip_bfloat16* dst = Pselb + (size_t)j * D_;
        for (int d = threadIdx.x; d < D_; d += 256)
            dst[d] = __float2bfloat16(src[d]);
    } else if (blk < 13604) {
        __shared__ __attribute__((aligned(16))) float wk[D_];
        for (int i = threadIdx.x; i < D_; i += 256) wk[i] = Wkc[i];
        __syncthreads();
        int idx = (blk - 13568) * 256 + threadIdx.x;
        int h = idx / D_, d = idx - h * D_;
        const float4* row = (const float4*)(Wqc + (size_t)d * D_ + h * 64);
        const float4* wkv = (const float4*)(wk + h * 64);
        float a0 = 0.f, a1 = 0.f, a2 = 0.f, a3 = 0.f;
#pragma unroll
        for (int j = 0; j < 16; j += 4) {
            float4 r0 = row[j], r1 = row[j + 1], r2 = row[j + 2], r3 = row[j + 3];
            float4 c0 = wkv[j], c1 = wkv[j + 1], c2 = wkv[j + 2], c3 = wkv[j + 3];
            a0 += r0.x * c0.x + r0.y * c0.y + r0.z * c0.z + r0.w * c0.w;
            a1 += r1.x * c1.x + r1.y * c1.y + r1.z * c1.z + r1.w * c1.w;
            a2 += r2.x * c2.x + r2.y * c2.y + r2.z * c2.z + r2.w * c2.w;
            a3 += r3.x * c3.x + r3.y * c3.y + r3.z * c3.z + r3.w * c3.w;
        }
        Ut[idx] = (a0 + a1) + (a2 + a3);
        if (idx < H_) {
            const float4* bq4 = (const float4*)(bqc + idx * 64);
            const float4* wk4 = (const float4*)(wk + idx * 64);
            float sAcc = 0.f;
#pragma unroll
            for (int j = 0; j < 16; ++j) {
                float4 bb = bq4[j], cc = wk4[j];
                sAcc += bb.x * cc.x + bb.y * cc.y + bb.z * cc.z + bb.w * cc.w;
            }
            ab[idx] = sAcc;
        }
    } else if (blk < 13640) {
        __shared__ float wv[D_];
        for (int i = threadIdx.x; i < D_; i += 256) wv[i] = Wvc[i];
        __syncthreads();
        int idx = (blk - 13604) * 256 + threadIdx.x;
        int h = idx / D_, n = idx - h * D_;
        float a[8] = {};
#pragma unroll
        for (int j = 0; j < 64; ++j)
            a[j & 7] += wv[h * 64 + j] * Woc[(size_t)(h * 64 + j) * D_ + n];
        Wmix[idx] = ((a[0] + a[1]) + (a[2] + a[3])) + ((a[4] + a[5]) + (a[6] + a[7]));
    } else if (blk < 13652) {
        int tx = threadIdx.x & 63, ty = threadIdx.x >> 6;
        int n = (blk - 13640) * 64 + tx;
        int d0 = ty * 192;
        float a = 0.f;
#pragma unroll 8
        for (int d = 0; d < 192; ++d)
            a += bvc[d0 + d] * Woc[(size_t)(d0 + d) * D_ + n];
        __shared__ float red[4][64];
        red[ty][tx] = a;
        __syncthreads();
        if (ty == 0)
            bias2[n] = boc[n] + red[0][tx] + red[1][tx] + red[2][tx] + red[3][tx];
    } else {
        int i = (blk - 13652) * 256 + threadIdx.x;
        bkv[i] = (i < D_) ? bk[i] : bv[i - D_];
    }
}

// ---------------------------------------------------------------------------
// MFMA sparse attention; K/V from merged kv buffer (row stride 1536, V at +768)
// ---------------------------------------------------------------------------
__global__ __launch_bounds__(256) void attn3_kernel(
    const u16* __restrict__ qb, const u16* __restrict__ kvb,
    const int* __restrict__ sel, u16* __restrict__ out)
{
    const int KV = 2 * D_;
    const int bh = blockIdx.y;
    const int b = bh / H_, h = bh % H_;
    const int s0 = blockIdx.x * 256;
    const int t = threadIdx.x;
    const int w = t >> 6, lane = t & 63;
    const int r = lane & 15, qd = lane >> 4;

    __shared__ u16 Vt[64][136];
    __shared__ u16 Plds[4][32][136];
    __shared__ int ssel[128];

    {
        int key0 = t >> 4;
        int d0 = (t & 15) * 4;
        for (int kk = key0; kk < 128; kk += 16) {
            ushort4 v = *(const ushort4*)(kvb + (size_t)(b * 128 + kk) * KV + D_ + h * 64 + d0);
            Vt[d0 + 0][kk] = v.x; Vt[d0 + 1][kk] = v.y;
            Vt[d0 + 2][kk] = v.z; Vt[d0 + 3][kk] = v.w;
        }
        if (t < 128) ssel[t] = sel[b * 128 + t];
    }
    __syncthreads();

    int selv[8];
#pragma unroll
    for (int n = 0; n < 8; ++n) selv[n] = ssel[n * 16 + r];

    for (int pass = 0; pass < 2; ++pass) {
        const int sbase = s0 + w * 64 + pass * 32;
        f32x4 accs[2][8] = {};

#pragma unroll
        for (int ks = 0; ks < 2; ++ks) {
            bf16x8 af[2];
#pragma unroll
            for (int m = 0; m < 2; ++m)
                af[m] = *(const bf16x8*)(qb + (size_t)(b * S_ + sbase + m * 16 + r) * D_ + h * 64 + ks * 32 + qd * 8);
#pragma unroll
            for (int n = 0; n < 8; ++n) {
                bf16x8 bfv = *(const bf16x8*)(kvb + (size_t)(b * 128 + n * 16 + r) * KV + h * 64 + ks * 32 + qd * 8);
#pragma unroll
                for (int m = 0; m < 2; ++m)
                    accs[m][n] = __builtin_amdgcn_mfma_f32_16x16x32_bf16(
                        af[m], bfv, accs[m][n], 0, 0, 0);
            }
        }

#pragma unroll
        for (int m = 0; m < 2; ++m) {
#pragma unroll
            for (int i = 0; i < 4; ++i) {
                int srow = sbase + m * 16 + qd * 4 + i;
                float pm = -3e38f;
#pragma unroll
                for (int n = 0; n < 8; ++n) {
                    float sc = accs[m][n][i] * 0.125f;
                    if (selv[n] > srow) sc = -1e9f;
                    accs[m][n][i] = sc;
                    pm = fmaxf(pm, sc);
                }
#pragma unroll
                for (int off = 1; off < 16; off <<= 1)
                    pm = fmaxf(pm, __shfl_xor(pm, off, 64));
                float ps = 0.f;
#pragma unroll
                for (int n = 0; n < 8; ++n) {
                    float e = __expf(accs[m][n][i] - pm);
                    accs[m][n][i] = e;
                    ps += e;
                }
#pragma unroll
                for (int off = 1; off < 16; off <<= 1)
                    ps += __shfl_xor(ps, off, 64);
                float inv = 1.0f / ps;
#pragma unroll
                for (int n = 0; n < 8; ++n)
                    accs[m][n][i] *= inv;
            }
        }

#pragma unroll
        for (int m = 0; m < 2; ++m)
#pragma unroll
            for (int n = 0; n < 8; ++n)
#pragma unroll
                for (int i = 0; i < 4; ++i) {
                    __hip_bfloat16 pb = __float2bfloat16(accs[m][n][i]);
                    Plds[w][m * 16 + qd * 4 + i][n * 16 + r] = *(u16*)&pb;
                }

        f32x4 acco[2][4] = {};
#pragma unroll
        for (int ks = 0; ks < 4; ++ks) {
            bf16x8 pa[2];
#pragma unroll
            for (int m = 0; m < 2; ++m)
                pa[m] = *(const bf16x8*)&Plds[w][m * 16 + r][ks * 32 + qd * 8];
#pragma unroll
            for (int nd = 0; nd < 4; ++nd) {
                bf16x8 bv = *(const bf16x8*)&Vt[nd * 16 + r][ks * 32 + qd * 8];
#pragma unroll
                for (int m = 0; m < 2; ++m)
                    acco[m][nd] = __builtin_amdgcn_mfma_f32_16x16x32_bf16(
                        pa[m], bv, acco[m][nd], 0, 0, 0);
            }
        }

#pragma unroll
        for (int m = 0; m < 2; ++m)
#pragma unroll
            for (int nd = 0; nd < 4; ++nd)
#pragma unroll
                for (int i = 0; i < 4; ++i) {
                    __hip_bfloat16 ob = __float2bfloat16(acco[m][nd][i]);
                    out[(size_t)(b * S_ + sbase + m * 16 + qd * 4 + i) * D_ + h * 64 + nd * 16 + r] = *(u16*)&ob;
                }
    }
}

// ---------------------------------------------------------------------------
// final LN: out[row] = LN(bf16 xa + bf16 xb)*g+beta. 192 threads, ushort4.
// ---------------------------------------------------------------------------
__global__ __launch_bounds__(192) void addln_bb(
    const u16* __restrict__ xa, const u16* __restrict__ xb,
    const float* __restrict__ g, const float* __restrict__ beta,
    float* __restrict__ out)
{
    const int row = blockIdx.x;
    const int t = threadIdx.x;
    const ushort4 a = ((const ushort4*)(xa + (size_t)row * D_))[t];
    const ushort4 b4 = ((const ushort4*)(xb + (size_t)row * D_))[t];
    float v[4] = {bfu2f(a.x) + bfu2f(b4.x), bfu2f(a.y) + bfu2f(b4.y),
                  bfu2f(a.z) + bfu2f(b4.z), bfu2f(a.w) + bfu2f(b4.w)};
    float sum = v[0] + v[1] + v[2] + v[3];
#pragma unroll
    for (int off = 1; off < 64; off <<= 1) sum += __shfl_xor(sum, off, 64);
    __shared__ float r1[3], r2[3];
    int wv = t >> 6, ln = t & 63;
    if (ln == 0) r1[wv] = sum;
    __syncthreads();
    float mean = (r1[0] + r1[1] + r1[2]) * (1.0f / 768.0f);
    float sq = 0.f;
#pragma unroll
    for (int i = 0; i < 4; ++i) { v[i] -= mean; sq += v[i] * v[i]; }
#pragma unroll
    for (int off = 1; off < 64; off <<= 1) sq += __shfl_xor(sq, off, 64);
    if (ln == 0) r2[wv] = sq;
    __syncthreads();
    float var = (r2[0] + r2[1] + r2[2]) * (1.0f / 768.0f);
    float rs = rsqrtf(var + 1e-5f);
    float4 gg = ((const float4*)g)[t];
    float4 bb = ((const float4*)beta)[t];
    float4 o;
    o.x = v[0] * rs * gg.x + bb.x;
    o.y = v[1] * rs * gg.y + bb.y;
    o.z = v[2] * rs * gg.z + bb.z;
    o.w = v[3] * rs * gg.w + bb.w;
    ((float4*)(out + (size_t)row * D_))[t] = o;
}

// ---------------------------------------------------------------------------
// Fused mid v5 — ONE ROW PER WAVE (grid M/4, 4 waves/block):
// x1=LN(cur+oproj); alpha=0.125*(x1@Ut+ab); mu=softmax-weighted cv sum
// (4 lanes per (row,h): 16 float4-iters each + 2-step shfl combine);
// x2=LN(x1+bias2+mu@Wmix) -> bf16 (in-place over curb, row-local).
// LDS ~15KB -> high residency; serial chains halved vs v4.
// ---------------------------------------------------------------------------
__global__ __launch_bounds__(256) void fused_mid(
    const u16* __restrict__ curb, const u16* __restrict__ oprojb,
    const float* __restrict__ g1, const float* __restrict__ b1,
    const float* __restrict__ Ut, const float* __restrict__ ab,
    const float* __restrict__ cvec,
    const float* __restrict__ Wmix, const float* __restrict__ bias2,
    const float* __restrict__ g2, const float* __restrict__ b2,
    __hip_bfloat16* __restrict__ x2b)
{
    const int w = threadIdx.x >> 6, lane = threadIdx.x & 63;
    const int row = blockIdx.x * 4 + w;
    const int b = blockIdx.x >> 10;          // 1024 blocks per batch

    __shared__ float4 cvs[64];
    __shared__ float xp[4][64][13];
    __shared__ float muls[4][12];

    if (threadIdx.x < 64)
        cvs[threadIdx.x] = ((const float4*)(cvec + b * C_))[threadIdx.x];

    // ---- x1 = LN(cur + oproj); lane owns elems i*256 + lane*4 + {0..3}
    float4 x1[3];
    {
        const ushort4* pa = (const ushort4*)(curb + (size_t)row * D_);
        const ushort4* pb = (const ushort4*)(oprojb + (size_t)row * D_);
        float s = 0.f;
#pragma unroll
        for (int i = 0; i < 3; ++i) {
            ushort4 au = pa[i * 64 + lane];
            ushort4 ou = pb[i * 64 + lane];
            float4 v;
            v.x = bfu2f(au.x) + bfu2f(ou.x); v.y = bfu2f(au.y) + bfu2f(ou.y);
            v.z = bfu2f(au.z) + bfu2f(ou.z); v.w = bfu2f(au.w) + bfu2f(ou.w);
            x1[i] = v;
            s += v.x + v.y + v.z + v.w;
        }
#pragma unroll
        for (int off = 1; off < 64; off <<= 1) s += __shfl_xor(s, off, 64);
        float mean = s * (1.0f / 768.0f);
        float sq = 0.f;
#pragma unroll
        for (int i = 0; i < 3; ++i) {
            x1[i].x -= mean; x1[i].y -= mean; x1[i].z -= mean; x1[i].w -= mean;
            sq += x1[i].x * x1[i].x + x1[i].y * x1[i].y
                + x1[i].z * x1[i].z + x1[i].w * x1[i].w;
        }
#pragma unroll
        for (int off = 1; off < 64; off <<= 1) sq += __shfl_xor(sq, off, 64);
        float rs = rsqrtf(sq * (1.0f / 768.0f) + 1e-5f);
#pragma unroll
        for (int i = 0; i < 3; ++i) {
            float4 gg = ((const float4*)g1)[i * 64 + lane];
            float4 bb = ((const float4*)b1)[i * 64 + lane];
            x1[i].x = x1[i].x * rs * gg.x + bb.x;
            x1[i].y = x1[i].y * rs * gg.y + bb.y;
            x1[i].z = x1[i].z * rs * gg.z + bb.z;
            x1[i].w = x1[i].w * rs * gg.w + bb.w;
        }
    }

    // ---- alpha partials: acc[h] = sum over this lane's 12 elems
    float acc[12];
#pragma unroll
    for (int h = 0; h < 12; ++h) acc[h] = 0.f;
#pragma unroll
    for (int i = 0; i < 3; ++i) {
#pragma unroll
        for (int h = 0; h < 12; ++h) {
            float4 u = ((const float4*)(Ut + (size_t)h * D_))[i * 64 + lane];
            acc[h] += x1[i].x * u.x + x1[i].y * u.y + x1[i].z * u.z + x1[i].w * u.w;
        }
    }
#pragma unroll
    for (int j = 0; j < 12; ++j) xp[w][lane][j] = acc[j];
    __syncthreads();

    // ---- alpha reduce + class softmax: 4 lanes per h (48 lanes active)
    if (lane < 48) {
        int h = lane >> 2, q = lane & 3;
        float ssum = 0.f;
#pragma unroll
        for (int k = 0; k < 16; ++k) ssum += xp[w][q * 16 + k][h];
        ssum += __shfl_xor(ssum, 1, 64);
        ssum += __shfl_xor(ssum, 2, 64);
        float a = 0.125f * (ssum + ab[h]);
        float z = 0.f, ms = 0.f;
#pragma unroll
        for (int it = 0; it < 16; ++it) {
            float4 c = cvs[q * 16 + it];
            float e0 = __expf(a * c.x), e1 = __expf(a * c.y),
                  e2 = __expf(a * c.z), e3 = __expf(a * c.w);
            z += e0 + e1 + e2 + e3;
            ms += e0 * c.x + e1 * c.y + e2 * c.z + e3 * c.w;
        }
        z += __shfl_xor(z, 1, 64);
        z += __shfl_xor(z, 2, 64);
        ms += __shfl_xor(ms, 1, 64);
        ms += __shfl_xor(ms, 2, 64);
        if (q == 0) muls[w][h] = ms / z;
    }
    __syncthreads();

    // ---- t2 = x1 + bias2 + mu@Wmix; x2 = LN(t2) -> bf16
    float4 t2[3];
#pragma unroll
    for (int i = 0; i < 3; ++i) {
        float4 o = ((const float4*)bias2)[i * 64 + lane];
#pragma unroll
        for (int h = 0; h < 12; ++h) {
            float4 wm = ((const float4*)(Wmix + (size_t)h * D_))[i * 64 + lane];
            float m0 = muls[w][h];
            o.x += m0 * wm.x; o.y += m0 * wm.y; o.z += m0 * wm.z; o.w += m0 * wm.w;
        }
        t2[i].x = x1[i].x + o.x; t2[i].y = x1[i].y + o.y;
        t2[i].z = x1[i].z + o.z; t2[i].w = x1[i].w + o.w;
    }
    {
        float s = 0.f;
#pragma unroll
        for (int i = 0; i < 3; ++i)
            s += t2[i].x + t2[i].y + t2[i].z + t2[i].w;
#pragma unroll
        for (int off = 1; off < 64; off <<= 1) s += __shfl_xor(s, off, 64);
        float mean = s * (1.0f / 768.0f);
        float sq = 0.f;
#pragma unroll
        for (int i = 0; i < 3; ++i) {
            t2[i].x -= mean; t2[i].y -= mean; t2[i].z -= mean; t2[i].w -= mean;
            sq += t2[i].x * t2[i].x + t2[i].y * t2[i].y
                + t2[i].z * t2[i].z + t2[i].w * t2[i].w;
        }
#pragma unroll
        for (int off = 1; off < 64; off <<= 1) sq += __shfl_xor(sq, off, 64);
        float rs = rsqrtf(sq * (1.0f / 768.0f) + 1e-5f);
        size_t base = (size_t)row * D_;
#pragma unroll
        for (int i = 0; i < 3; ++i) {
            float4 gg = ((const float4*)g2)[i * 64 + lane];
            float4 bb = ((const float4*)b2)[i * 64 + lane];
            float vx = t2[i].x * rs * gg.x + bb.x;
            float vy = t2[i].y * rs * gg.y + bb.y;
            float vz = t2[i].z * rs * gg.z + bb.z;
            float vw = t2[i].w * rs * gg.w + bb.w;
            __hip_bfloat16 pk[4] = {
                __float2bfloat16(vx), __float2bfloat16(vy),
                __float2bfloat16(vz), __float2bfloat16(vw)};
            *(uint2*)(x2b + base + i * 256 + lane * 4) = *(const uint2*)pk;
        }
    }
}

// ---------------------------------------------------------------------------
extern "C" void kernel_launch(void* const* d_in, const int* in_sizes, int n_in,
                              void* d_out, int out_size, void* d_ws, size_t ws_size,
                              hipStream_t stream) {
    const float* cur   = (const float*)d_in[0];
    const float* prev  = (const float*)d_in[1];
    const float* cvec  = (const float*)d_in[2];
    const int*   ridx  = (const int*)d_in[3];
    const float* Wq  = (const float*)d_in[4];
    const float* bq  = (const float*)d_in[5];
    const float* Wk  = (const float*)d_in[6];
    const float* bk  = (const float*)d_in[7];
    const float* Wv  = (const float*)d_in[8];
    const float* bv  = (const float*)d_in[9];
    const float* Wo  = (const float*)d_in[10];
    const float* bo  = (const float*)d_in[11];
    const float* g1  = (const float*)d_in[12];
    const float* b1  = (const float*)d_in[13];
    const float* Wqc = (const float*)d_in[14];
    const float* bqc = (const float*)d_in[15];
    const float* Wkc = (const float*)d_in[16];
    const float* bkc = (const float*)d_in[17];  (void)bkc;
    const float* Wvc = (const float*)d_in[18];
    const float* bvc = (const float*)d_in[19];
    const float* Woc = (const float*)d_in[20];
    const float* boc = (const float*)d_in[21];
    const float* g2  = (const float*)d_in[22];
    const float* b2  = (const float*)d_in[23];
    const float* W1  = (const float*)d_in[24];
    const float* bf1 = (const float*)d_in[25];
    const float* W2  = (const float*)d_in[26];
    const float* bf2 = (const float*)d_in[27];
    const float* g3  = (const float*)d_in[28];
    const float* b3  = (const float*)d_in[29];
    float* outp = (float*)d_out;
    (void)ws_size; (void)in_sizes; (void)n_in; (void)out_size;

    const int M = B_ * S_;                       // 16384
    const size_t NBSD = (size_t)M * D_;          // 12,582,912
    const size_t NSEL = (size_t)B_ * 128 * D_;   // 393,216

    __hip_bfloat16* hidb  = (__hip_bfloat16*)d_ws;          // M x FF (attn_out, then hid)
    __hip_bfloat16* bf0   = hidb + (size_t)M * FF_;         // cur_bf -> x2
    __hip_bfloat16* tmpb  = bf0 + NBSD;                     // q -> oproj -> ff
    __hip_bfloat16* Pselb = tmpb + NBSD;
    __hip_bfloat16* kvselb = Pselb + NSEL;                  // merged K|V, 512 x 1536
    __hip_bfloat16* Wqt   = kvselb + 2 * NSEL;
    __hip_bfloat16* Wot   = Wqt + (size_t)D_ * D_;
    __hip_bfloat16* Wkt   = Wot + (size_t)D_ * D_;          // Wkt||Wvt = [1536][768]
    __hip_bfloat16* Wvt   = Wkt + (size_t)D_ * D_;
    __hip_bfloat16* W1t   = Wvt + (size_t)D_ * D_;          // FF x D
    __hip_bfloat16* W2t   = W1t + (size_t)D_ * FF_;         // D x FF
    float* Ub    = (float*)(W2t + (size_t)FF_ * D_);
    float* abv   = Ub + (size_t)D_ * H_;
    float* Wmix  = abv + 16;
    float* bias2 = Wmix + (size_t)H_ * D_;
    int*   selb  = (int*)(bias2 + D_);
    float* bkv   = (float*)(selb + 512);                    // 1536 floats

    // 1) ALL independent prep in ONE dispatch
    preamble<<<PRE_NBLK, 256, 0, stream>>>(
        cur, prev, ridx, Wq, Wo, Wk, Wv, W1, W2,
        Wqc, Wkc, bqc, Wvc, Woc, bvc, boc, bk, bv,
        Pselb, selb, bf0, Wqt, Wot, Wkt, Wvt, W1t, W2t,
        Ub, abv, Wmix, bias2, bkv);

    // 2) q-proj + merged K|V-proj in ONE dispatch (816 blocks)
    gemm128_qkv<<<816, 512, 0, stream>>>(
        (const u16*)bf0, (const u16*)Wqt, bq, (u16*)tmpb,
        (const u16*)Pselb, (const u16*)Wkt, bkv, (u16*)kvselb);

    // 3) MFMA sparse attention -> hidb (cur_bf preserved in bf0)
    attn3_kernel<<<dim3(S_ / 256, B_ * H_), 256, 0, stream>>>(
        (const u16*)tmpb, (const u16*)kvselb, selb, (u16*)hidb);

    // 4) oproj = attn_out @ Wo + bo -> tmpb (q dead)
    gemm128<<<dim3(D_ / 128, M / 128), 512, 0, stream>>>(
        (const u16*)hidb, (const u16*)Wot, bo, (u16*)tmpb, M, D_, D_, 1);

    // 5) fused mid v5: 1 row/wave -> bf0 (in-place over cur_bf)
    fused_mid<<<M / 4, 256, 0, stream>>>(
        (const u16*)bf0, (const u16*)tmpb, g1, b1, Ub, abv, cvec, Wmix, bias2,
        g2, b2, bf0);

    // 6) FF via 8-phase 256^2: hid -> hidb (768 blocks); ff -> tmpb (192)
    gemm256<<<dim3(FF_ / 256, M / 256), 512, 0, stream>>>(
        (const u16*)bf0, (const u16*)W1t, bf1, (u16*)hidb, M, FF_, D_, 1 | 2);
    gemm256<<<dim3(D_ / 256, M / 256), 512, 0, stream>>>(
        (const u16*)hidb, (const u16*)W2t, bf2, (u16*)tmpb, M, D_, FF_, 1);

    // 7) out = LN(x2 + ff)
    addln_bb<<<M, 192, 0, stream>>>((const u16*)bf0, (const u16*)tmpb, g3, b3, outp);
}

// Round 20
// 372.757 us; speedup vs baseline: 1.0338x; 1.0338x over previous
//
#include <hip/hip_runtime.h>
#include <hip/hip_bf16.h>

#define B_ 4
#define S_ 4096
#define D_ 768
#define H_ 12
#define DH_ 64
#define G_ 64
#define C_ 256
#define FF_ 3072

typedef __attribute__((ext_vector_type(8))) short bf16x8;
typedef __attribute__((ext_vector_type(4))) float f32x4;
typedef unsigned short u16;

__device__ __forceinline__ float bfu2f(u16 u) {
    return __uint_as_float((unsigned)u << 16);
}

// ---------------------------------------------------------------------------
// async global->LDS 16B (wave-uniform LDS base + lane*16)
// ---------------------------------------------------------------------------
__device__ __forceinline__ void gload16(const __hip_bfloat16* g, __hip_bfloat16* l) {
    __builtin_amdgcn_global_load_lds(
        (__attribute__((address_space(1))) void*)(void*)const_cast<__hip_bfloat16*>(g),
        (__attribute__((address_space(3))) void*)(void*)l,
        16, 0, 0);
}

// ---------------------------------------------------------------------------
// gemm256 — 8-phase schedule (r10 verbatim): 256x256 tile, BK=64, 8 waves.
// A: MxK bf16, Bt: NxK bf16. Out bf16. flags: 1=bias, 2=relu.
// M%256==0, N%256==0, K%128==0, nwg%8==0.
// ---------------------------------------------------------------------------
__global__ __launch_bounds__(512, 2) void gemm256(
    const u16* __restrict__ A, const u16* __restrict__ Bt,
    const float* __restrict__ bias, u16* __restrict__ Cb,
    int M, int N, int K, int flags)
{
    __shared__ __attribute__((aligned(16))) u16 Ah[2][2][128 * 64];
    __shared__ __attribute__((aligned(16))) u16 Bh[2][2][128 * 64];

    const int tid = threadIdx.x;
    const int lane = tid & 63, w = tid >> 6;
    const int wm = w >> 2, wn = w & 3;
    const int r = lane & 15, qd = lane >> 4;

    int lin = blockIdx.y * gridDim.x + blockIdx.x;
    int nwg = gridDim.x * gridDim.y;
    int cpx = nwg >> 3;
    int swz = (lin & 7) * cpx + (lin >> 3);
    int bm = (swz / gridDim.x) * 256;
    int bn = (swz % gridDim.x) * 256;

    const int srow = tid >> 3;
    const int scol = ((tid & 7) ^ (srow & 7)) * 8;
    const int sdst = tid * 8;

#define STG_A(c, h, kt) { \
    const u16* s_ = A + (size_t)(bm + (h) * 128 + srow) * K + ((kt) << 6) + scol; \
    gload16((const __hip_bfloat16*)s_, (__hip_bfloat16*)&Ah[c][h][sdst]); \
    gload16((const __hip_bfloat16*)(s_ + (size_t)64 * K), (__hip_bfloat16*)&Ah[c][h][sdst + 4096]); }
#define STG_B(c, h, kt) { \
    const u16* s_ = Bt + (size_t)(bn + (h) * 128 + srow) * K + ((kt) << 6) + scol; \
    gload16((const __hip_bfloat16*)s_, (__hip_bfloat16*)&Bh[c][h][sdst]); \
    gload16((const __hip_bfloat16*)(s_ + (size_t)64 * K), (__hip_bfloat16*)&Bh[c][h][sdst + 4096]); }

#define GRAN(kk) (((((kk) << 2) + qd) ^ (r & 7)) * 8)
#define READS_AF(c, mb) { \
    _Pragma("unroll") for (int m = 0; m < 4; ++m) { \
        const u16* p_ = &Ah[c][wm][((mb + m) * 16 + r) * 64]; \
        af[m][0] = *(const bf16x8*)(p_ + GRAN(0)); \
        af[m][1] = *(const bf16x8*)(p_ + GRAN(1)); } }
#define READS_BF(dst, c, nb) { \
    _Pragma("unroll") for (int n = 0; n < 2; ++n) { \
        const u16* p_ = &Bh[c][wn >> 1][((wn & 1) * 64 + (nb + n) * 16 + r) * 64]; \
        dst[n][0] = *(const bf16x8*)(p_ + GRAN(0)); \
        dst[n][1] = *(const bf16x8*)(p_ + GRAN(1)); } }
#define QMFMA(mb, nb, bfx) { \
    __builtin_amdgcn_s_setprio(1); \
    _Pragma("unroll") for (int kk = 0; kk < 2; ++kk) \
    _Pragma("unroll") for (int m = 0; m < 4; ++m) \
    _Pragma("unroll") for (int n = 0; n < 2; ++n) \
        acc[mb + m][nb + n] = __builtin_amdgcn_mfma_f32_16x16x32_bf16( \
            af[m][kk], bfx[n][kk], acc[mb + m][nb + n], 0, 0, 0); \
    __builtin_amdgcn_s_setprio(0); }
#define BAR() __builtin_amdgcn_s_barrier()
#define LGKM0() asm volatile("s_waitcnt lgkmcnt(0)" ::: "memory")

    f32x4 acc[8][4] = {};
    const int NT = K >> 6;
    const int J = NT >> 1;

    bf16x8 af[4][2], bfa[2][2], bfb[2][2];

    STG_A(0, 0, 0) STG_A(0, 1, 0) STG_B(0, 0, 0) STG_B(0, 1, 0)
    STG_A(1, 0, 1) STG_A(1, 1, 1)
    asm volatile("s_waitcnt vmcnt(4)" ::: "memory");
    BAR();
    READS_AF(0, 0) READS_BF(bfa, 0, 0)

    for (int j = 0; j < J; ++j) {
        const int to1 = 2 * j + 1, te2 = 2 * j + 2, to3 = 2 * j + 3;
        const bool pf = (j + 1 < J);

        STG_B(1, 0, to1)
        BAR(); LGKM0();
        QMFMA(0, 0, bfa)
        READS_BF(bfb, 0, 2)
        BAR();
        STG_B(1, 1, to1)
        BAR(); LGKM0();
        QMFMA(0, 2, bfb)
        READS_AF(0, 4)
        BAR();
        LGKM0();
        QMFMA(4, 2, bfb)
        BAR();
        if (pf) { STG_A(0, 0, te2) STG_A(0, 1, te2) }
        BAR();
        QMFMA(4, 0, bfa)
        if (pf) asm volatile("s_waitcnt vmcnt(4)" ::: "memory");
        else    asm volatile("s_waitcnt vmcnt(0)" ::: "memory");
        BAR();
        READS_AF(1, 0) READS_BF(bfa, 1, 0)
        if (pf) { STG_B(0, 0, te2) }
        BAR(); LGKM0();
        QMFMA(0, 0, bfa)
        READS_BF(bfb, 1, 2)
        BAR();
        if (pf) { STG_B(0, 1, te2) }
        BAR(); LGKM0();
        QMFMA(0, 2, bfb)
        READS_AF(1, 4)
        BAR();
        LGKM0();
        QMFMA(4, 2, bfb)
        BAR();
        if (pf) { STG_A(1, 0, to3) STG_A(1, 1, to3) }
        BAR();
        QMFMA(4, 0, bfa)
        if (pf) {
            asm volatile("s_waitcnt vmcnt(4)" ::: "memory");
            BAR();
            READS_AF(0, 0) READS_BF(bfa, 0, 0)
        }
    }

#pragma unroll
    for (int m = 0; m < 8; ++m) {
        int row0 = bm + wm * 128 + m * 16 + qd * 4;
#pragma unroll
        for (int n = 0; n < 4; ++n) {
            int col = bn + wn * 64 + n * 16 + r;
            float bv = (flags & 1) ? bias[col] : 0.0f;
#pragma unroll
            for (int i = 0; i < 4; ++i) {
                float v = acc[m][n][i] + bv;
                if (flags & 2) v = fmaxf(v, 0.0f);
                __hip_bfloat16 ob = __float2bfloat16(v);
                Cb[(size_t)(row0 + i) * N + col] = *(u16*)&ob;
            }
        }
    }
#undef STG_A
#undef STG_B
#undef GRAN
#undef READS_AF
#undef READS_BF
#undef QMFMA
#undef BAR
#undef LGKM0
}

// ---------------------------------------------------------------------------
// gemm128 body — 128x128, BK=64, 8 waves; single-barrier stage-first 2-phase.
// ---------------------------------------------------------------------------
__device__ __forceinline__ void gemm128_body(
    const u16* __restrict__ A, const u16* __restrict__ Bt,
    const float* __restrict__ bias, u16* __restrict__ Cb,
    int M, int N, int K, int flags, int bm, int bn)
{
    __shared__ __attribute__((aligned(16))) u16 As[2][128 * 64];
    __shared__ __attribute__((aligned(16))) u16 Bs[2][128 * 64];

    const int tid = threadIdx.x;
    const int lane = tid & 63, w = tid >> 6;
    const int wm = w >> 2, wn = w & 3;
    const int r = lane & 15, qd = lane >> 4;

    const int srow = tid >> 3;
    const int sg = ((tid & 7) ^ (srow & 7)) * 8;

#define STG(c, kt) { \
    const u16* a_ = A + (size_t)(bm + srow) * K + ((kt) << 6) + sg; \
    gload16((const __hip_bfloat16*)a_, (__hip_bfloat16*)&As[c][tid * 8]); \
    gload16((const __hip_bfloat16*)(a_ + (size_t)64 * K), (__hip_bfloat16*)&As[c][4096 + tid * 8]); \
    const u16* b_ = Bt + (size_t)(bn + srow) * K + ((kt) << 6) + sg; \
    gload16((const __hip_bfloat16*)b_, (__hip_bfloat16*)&Bs[c][tid * 8]); \
    gload16((const __hip_bfloat16*)(b_ + (size_t)64 * K), (__hip_bfloat16*)&Bs[c][4096 + tid * 8]); }

#define GR(kk) (((((kk) << 2) + qd) ^ (r & 7)) * 8)

    f32x4 acc[4][2] = {};
    const int NT = K >> 6;

    STG(0, 0)
    asm volatile("s_waitcnt vmcnt(0)" ::: "memory");
    __builtin_amdgcn_s_barrier();

    for (int kt = 0; kt < NT; ++kt) {
        const int c = kt & 1;
        if (kt + 1 < NT) STG(c ^ 1, kt + 1)
        const u16* as = As[c];
        const u16* bs = Bs[c];
#pragma unroll
        for (int kk = 0; kk < 2; ++kk) {
            bf16x8 af[4], bf[2];
#pragma unroll
            for (int m = 0; m < 4; ++m)
                af[m] = *(const bf16x8*)&as[(wm * 64 + m * 16 + r) * 64 + GR(kk)];
#pragma unroll
            for (int n = 0; n < 2; ++n)
                bf[n] = *(const bf16x8*)&bs[(wn * 32 + n * 16 + r) * 64 + GR(kk)];
            __builtin_amdgcn_s_setprio(1);
#pragma unroll
            for (int m = 0; m < 4; ++m)
#pragma unroll
                for (int n = 0; n < 2; ++n)
                    acc[m][n] = __builtin_amdgcn_mfma_f32_16x16x32_bf16(
                        af[m], bf[n], acc[m][n], 0, 0, 0);
            __builtin_amdgcn_s_setprio(0);
        }
        asm volatile("s_waitcnt vmcnt(0)" ::: "memory");
        __builtin_amdgcn_s_barrier();
    }

#pragma unroll
    for (int m = 0; m < 4; ++m) {
        int row0 = bm + wm * 64 + m * 16 + qd * 4;
#pragma unroll
        for (int n = 0; n < 2; ++n) {
            int col = bn + wn * 32 + n * 16 + r;
            float bv = (flags & 1) ? bias[col] : 0.0f;
#pragma unroll
            for (int i = 0; i < 4; ++i) {
                float v = acc[m][n][i] + bv;
                if (flags & 2) v = fmaxf(v, 0.0f);
                __hip_bfloat16 ob = __float2bfloat16(v);
                Cb[(size_t)(row0 + i) * N + col] = *(u16*)&ob;
            }
        }
    }
#undef STG
#undef GR
}

// plain gemm128 (oproj): own XCD swizzle
__global__ __launch_bounds__(512, 4) void gemm128(
    const u16* __restrict__ A, const u16* __restrict__ Bt,
    const float* __restrict__ bias, u16* __restrict__ Cb,
    int M, int N, int K, int flags)
{
    int lin = blockIdx.y * gridDim.x + blockIdx.x;
    int nwg = gridDim.x * gridDim.y;
    int cpx = nwg >> 3;
    int swz = (lin & 7) * cpx + (lin >> 3);
    int bm = (swz / gridDim.x) * 128;
    int bn = (swz % gridDim.x) * 128;
    gemm128_body(A, Bt, bias, Cb, M, N, K, flags, bm, bn);
}

// fused q-proj + kv-proj in ONE dispatch (816 blocks; 816 % 8 == 0).
__global__ __launch_bounds__(512, 4) void gemm128_qkv(
    const u16* __restrict__ curb, const u16* __restrict__ Wqt,
    const float* __restrict__ bq, u16* __restrict__ qout,
    const u16* __restrict__ Pselb, const u16* __restrict__ Wkvt,
    const float* __restrict__ bkv, u16* __restrict__ kvout)
{
    int lin = blockIdx.x;
    int nwg = gridDim.x;                 // 816
    int cpx = nwg >> 3;
    int swz = (lin & 7) * cpx + (lin >> 3);
    if (swz < 768) {
        int bm = (swz / 6) * 128, bn = (swz % 6) * 128;
        gemm128_body(curb, Wqt, bq, qout, B_ * S_, D_, D_, 1, bm, bn);
    } else {
        int s2 = swz - 768;
        int bm = (s2 / 12) * 128, bn = (s2 % 12) * 128;
        gemm128_body(Pselb, Wkvt, bkv, kvout, B_ * 128, 2 * D_, D_, 1, bm, bn);
    }
}

// ---------------------------------------------------------------------------
// preamble — ALL independent prep work in ONE dispatch (block-range routed)
// ---------------------------------------------------------------------------
#define PRE_NBLK 13658

__global__ __launch_bounds__(256) void preamble(
    const float* __restrict__ cur, const float* __restrict__ prev,
    const int* __restrict__ ridx,
    const float* __restrict__ Wq, const float* __restrict__ Wo,
    const float* __restrict__ Wk, const float* __restrict__ Wv,
    const float* __restrict__ W1, const float* __restrict__ W2,
    const float* __restrict__ Wqc, const float* __restrict__ Wkc,
    const float* __restrict__ bqc, const float* __restrict__ Wvc,
    const float* __restrict__ Woc, const float* __restrict__ bvc,
    const float* __restrict__ boc, const float* __restrict__ bk,
    const float* __restrict__ bv,
    __hip_bfloat16* __restrict__ Pselb, int* __restrict__ sel,
    __hip_bfloat16* __restrict__ curb,
    __hip_bfloat16* __restrict__ Wqt, __hip_bfloat16* __restrict__ Wot,
    __hip_bfloat16* __restrict__ Wkt, __hip_bfloat16* __restrict__ Wvt,
    __hip_bfloat16* __restrict__ W1t, __hip_bfloat16* __restrict__ W2t,
    float* __restrict__ Ut, float* __restrict__ ab,
    float* __restrict__ Wmix, float* __restrict__ bias2,
    float* __restrict__ bkv)
{
    int blk = blockIdx.x;
    if (blk < 6912) {
        int tile = blk;
        const float* W; __hip_bfloat16* Wt; int K, N;
        if (tile < 2304) {
            int w = tile / 576; tile -= w * 576;
            K = 768; N = 768;
            W  = (w == 0) ? Wq : (w == 1) ? Wo : (w == 2) ? Wk : Wv;
            Wt = (w == 0) ? Wqt : (w == 1) ? Wot : (w == 2) ? Wkt : Wvt;
        } else if (tile < 4608) { tile -= 2304; K = 768; N = 3072; W = W1; Wt = W1t; }
        else                    { tile -= 4608; K = 3072; N = 768; W = W2; Wt = W2t; }
        int ntx = N >> 5;
        int k0 = (tile / ntx) * 32, n0 = (tile % ntx) * 32;
        __shared__ float s[32][33];
        int tx = threadIdx.x & 31, ty = threadIdx.x >> 5;
#pragma unroll
        for (int i = 0; i < 4; ++i)
            s[ty + i * 8][tx] = W[(size_t)(k0 + ty + i * 8) * N + n0 + tx];
        __syncthreads();
#pragma unroll
        for (int i = 0; i < 4; ++i)
            Wt[(size_t)(n0 + ty + i * 8) * K + k0 + tx] =
                __float2bfloat16(s[tx][ty + i * 8]);
    } else if (blk < 13056) {
        int i = (blk - 6912) * 256 + threadIdx.x;
        const float4* p = (const float4*)(cur + (size_t)i * 8);
        float4 v0 = p[0], v1 = p[1];
        __hip_bfloat16 o[8] = {
            __float2bfloat16(v0.x), __float2bfloat16(v0.y),
            __float2bfloat16(v0.z), __float2bfloat16(v0.w),
            __float2bfloat16(v1.x), __float2bfloat16(v1.y),
            __float2bfloat16(v1.z), __float2bfloat16(v1.w)};
        *(uint4*)(curb + (size_t)i * 8) = *(const uint4*)o;
    } else if (blk < 13568) {
        int j = blk - 13056;
        int b = j >> 7, i = j & 127;
        int sv = (i < 64) ? i : ridx[b * G_ + (i - 64)];
        if (threadIdx.x == 0) sel[j] = sv;
        const float* src = prev + ((size_t)(b * S_ + sv)) * D_;
        __hip_bfloat16* dst = Pselb + (size_t)j * D_;
        for (int d = threadIdx.x; d < D_; d += 256)
            dst[d] = __float2bfloat16(src[d]);
    } else if (blk < 13604) {
        __shared__ __attribute__((aligned(16))) float wk[D_];
        for (int i = threadIdx.x; i < D_; i += 256) wk[i] = Wkc[i];
        __syncthreads();
        int idx = (blk - 13568) * 256 + threadIdx.x;
        int h = idx / D_, d = idx - h * D_;
        const float4* row = (const float4*)(Wqc + (size_t)d * D_ + h * 64);
        const float4* wkv = (const float4*)(wk + h * 64);
        float a0 = 0.f, a1 = 0.f, a2 = 0.f, a3 = 0.f;
#pragma unroll
        for (int j = 0; j < 16; j += 4) {
            float4 r0 = row[j], r1 = row[j + 1], r2 = row[j + 2], r3 = row[j + 3];
            float4 c0 = wkv[j], c1 = wkv[j + 1], c2 = wkv[j + 2], c3 = wkv[j + 3];
            a0 += r0.x * c0.x + r0.y * c0.y + r0.z * c0.z + r0.w * c0.w;
            a1 += r1.x * c1.x + r1.y * c1.y + r1.z * c1.z + r1.w * c1.w;
            a2 += r2.x * c2.x + r2.y * c2.y + r2.z * c2.z + r2.w * c2.w;
            a3 += r3.x * c3.x + r3.y * c3.y + r3.z * c3.z + r3.w * c3.w;
        }
        Ut[idx] = (a0 + a1) + (a2 + a3);
        if (idx < H_) {
            const float4* bq4 = (const float4*)(bqc + idx * 64);
            const float4* wk4 = (const float4*)(wk + idx * 64);
            float sAcc = 0.f;
#pragma unroll
            for (int j = 0; j < 16; ++j) {
                float4 bb = bq4[j], cc = wk4[j];
                sAcc += bb.x * cc.x + bb.y * cc.y + bb.z * cc.z + bb.w * cc.w;
            }
            ab[idx] = sAcc;
        }
    } else if (blk < 13640) {
        __shared__ float wv[D_];
        for (int i = threadIdx.x; i < D_; i += 256) wv[i] = Wvc[i];
        __syncthreads();
        int idx = (blk - 13604) * 256 + threadIdx.x;
        int h = idx / D_, n = idx - h * D_;
        float a[8] = {};
#pragma unroll
        for (int j = 0; j < 64; ++j)
            a[j & 7] += wv[h * 64 + j] * Woc[(size_t)(h * 64 + j) * D_ + n];
        Wmix[idx] = ((a[0] + a[1]) + (a[2] + a[3])) + ((a[4] + a[5]) + (a[6] + a[7]));
    } else if (blk < 13652) {
        int tx = threadIdx.x & 63, ty = threadIdx.x >> 6;
        int n = (blk - 13640) * 64 + tx;
        int d0 = ty * 192;
        float a = 0.f;
#pragma unroll 8
        for (int d = 0; d < 192; ++d)
            a += bvc[d0 + d] * Woc[(size_t)(d0 + d) * D_ + n];
        __shared__ float red[4][64];
        red[ty][tx] = a;
        __syncthreads();
        if (ty == 0)
            bias2[n] = boc[n] + red[0][tx] + red[1][tx] + red[2][tx] + red[3][tx];
    } else {
        int i = (blk - 13652) * 256 + threadIdx.x;
        bkv[i] = (i < D_) ? bk[i] : bv[i - D_];
    }
}

// ---------------------------------------------------------------------------
// MFMA sparse attention; K/V from merged kv buffer (row stride 1536, V at +768)
// ---------------------------------------------------------------------------
__global__ __launch_bounds__(256) void attn3_kernel(
    const u16* __restrict__ qb, const u16* __restrict__ kvb,
    const int* __restrict__ sel, u16* __restrict__ out)
{
    const int KV = 2 * D_;
    const int bh = blockIdx.y;
    const int b = bh / H_, h = bh % H_;
    const int s0 = blockIdx.x * 256;
    const int t = threadIdx.x;
    const int w = t >> 6, lane = t & 63;
    const int r = lane & 15, qd = lane >> 4;

    __shared__ u16 Vt[64][136];
    __shared__ u16 Plds[4][32][136];
    __shared__ int ssel[128];

    {
        int key0 = t >> 4;
        int d0 = (t & 15) * 4;
        for (int kk = key0; kk < 128; kk += 16) {
            ushort4 v = *(const ushort4*)(kvb + (size_t)(b * 128 + kk) * KV + D_ + h * 64 + d0);
            Vt[d0 + 0][kk] = v.x; Vt[d0 + 1][kk] = v.y;
            Vt[d0 + 2][kk] = v.z; Vt[d0 + 3][kk] = v.w;
        }
        if (t < 128) ssel[t] = sel[b * 128 + t];
    }
    __syncthreads();

    int selv[8];
#pragma unroll
    for (int n = 0; n < 8; ++n) selv[n] = ssel[n * 16 + r];

    for (int pass = 0; pass < 2; ++pass) {
        const int sbase = s0 + w * 64 + pass * 32;
        f32x4 accs[2][8] = {};

#pragma unroll
        for (int ks = 0; ks < 2; ++ks) {
            bf16x8 af[2];
#pragma unroll
            for (int m = 0; m < 2; ++m)
                af[m] = *(const bf16x8*)(qb + (size_t)(b * S_ + sbase + m * 16 + r) * D_ + h * 64 + ks * 32 + qd * 8);
#pragma unroll
            for (int n = 0; n < 8; ++n) {
                bf16x8 bfv = *(const bf16x8*)(kvb + (size_t)(b * 128 + n * 16 + r) * KV + h * 64 + ks * 32 + qd * 8);
#pragma unroll
                for (int m = 0; m < 2; ++m)
                    accs[m][n] = __builtin_amdgcn_mfma_f32_16x16x32_bf16(
                        af[m], bfv, accs[m][n], 0, 0, 0);
            }
        }

#pragma unroll
        for (int m = 0; m < 2; ++m) {
#pragma unroll
            for (int i = 0; i < 4; ++i) {
                int srow = sbase + m * 16 + qd * 4 + i;
                float pm = -3e38f;
#pragma unroll
                for (int n = 0; n < 8; ++n) {
                    float sc = accs[m][n][i] * 0.125f;
                    if (selv[n] > srow) sc = -1e9f;
                    accs[m][n][i] = sc;
                    pm = fmaxf(pm, sc);
                }
#pragma unroll
                for (int off = 1; off < 16; off <<= 1)
                    pm = fmaxf(pm, __shfl_xor(pm, off, 64));
                float ps = 0.f;
#pragma unroll
                for (int n = 0; n < 8; ++n) {
                    float e = __expf(accs[m][n][i] - pm);
                    accs[m][n][i] = e;
                    ps += e;
                }
#pragma unroll
                for (int off = 1; off < 16; off <<= 1)
                    ps += __shfl_xor(ps, off, 64);
                float inv = 1.0f / ps;
#pragma unroll
                for (int n = 0; n < 8; ++n)
                    accs[m][n][i] *= inv;
            }
        }

#pragma unroll
        for (int m = 0; m < 2; ++m)
#pragma unroll
            for (int n = 0; n < 8; ++n)
#pragma unroll
                for (int i = 0; i < 4; ++i) {
                    __hip_bfloat16 pb = __float2bfloat16(accs[m][n][i]);
                    Plds[w][m * 16 + qd * 4 + i][n * 16 + r] = *(u16*)&pb;
                }

        f32x4 acco[2][4] = {};
#pragma unroll
        for (int ks = 0; ks < 4; ++ks) {
            bf16x8 pa[2];
#pragma unroll
            for (int m = 0; m < 2; ++m)
                pa[m] = *(const bf16x8*)&Plds[w][m * 16 + r][ks * 32 + qd * 8];
#pragma unroll
            for (int nd = 0; nd < 4; ++nd) {
                bf16x8 bv = *(const bf16x8*)&Vt[nd * 16 + r][ks * 32 + qd * 8];
#pragma unroll
                for (int m = 0; m < 2; ++m)
                    acco[m][nd] = __builtin_amdgcn_mfma_f32_16x16x32_bf16(
                        pa[m], bv, acco[m][nd], 0, 0, 0);
            }
        }

#pragma unroll
        for (int m = 0; m < 2; ++m)
#pragma unroll
            for (int nd = 0; nd < 4; ++nd)
#pragma unroll
                for (int i = 0; i < 4; ++i) {
                    __hip_bfloat16 ob = __float2bfloat16(acco[m][nd][i]);
                    out[(size_t)(b * S_ + sbase + m * 16 + qd * 4 + i) * D_ + h * 64 + nd * 16 + r] = *(u16*)&ob;
                }
    }
}

// ---------------------------------------------------------------------------
// final LN: out[row] = LN(bf16 xa + bf16 xb)*g+beta. 192 threads, ushort4.
// ---------------------------------------------------------------------------
__global__ __launch_bounds__(192) void addln_bb(
    const u16* __restrict__ xa, const u16* __restrict__ xb,
    const float* __restrict__ g, const float* __restrict__ beta,
    float* __restrict__ out)
{
    const int row = blockIdx.x;
    const int t = threadIdx.x;
    const ushort4 a = ((const ushort4*)(xa + (size_t)row * D_))[t];
    const ushort4 b4 = ((const ushort4*)(xb + (size_t)row * D_))[t];
    float v[4] = {bfu2f(a.x) + bfu2f(b4.x), bfu2f(a.y) + bfu2f(b4.y),
                  bfu2f(a.z) + bfu2f(b4.z), bfu2f(a.w) + bfu2f(b4.w)};
    float sum = v[0] + v[1] + v[2] + v[3];
#pragma unroll
    for (int off = 1; off < 64; off <<= 1) sum += __shfl_xor(sum, off, 64);
    __shared__ float r1[3], r2[3];
    int wv = t >> 6, ln = t & 63;
    if (ln == 0) r1[wv] = sum;
    __syncthreads();
    float mean = (r1[0] + r1[1] + r1[2]) * (1.0f / 768.0f);
    float sq = 0.f;
#pragma unroll
    for (int i = 0; i < 4; ++i) { v[i] -= mean; sq += v[i] * v[i]; }
#pragma unroll
    for (int off = 1; off < 64; off <<= 1) sq += __shfl_xor(sq, off, 64);
    if (ln == 0) r2[wv] = sq;
    __syncthreads();
    float var = (r2[0] + r2[1] + r2[2]) * (1.0f / 768.0f);
    float rs = rsqrtf(var + 1e-5f);
    float4 gg = ((const float4*)g)[t];
    float4 bb = ((const float4*)beta)[t];
    float4 o;
    o.x = v[0] * rs * gg.x + bb.x;
    o.y = v[1] * rs * gg.y + bb.y;
    o.z = v[2] * rs * gg.z + bb.z;
    o.w = v[3] * rs * gg.w + bb.w;
    ((float4*)(out + (size_t)row * D_))[t] = o;
}

// ---------------------------------------------------------------------------
// Fused mid (r18 version): 2 rows/wave, grid M/8.
// x1=LN(cur_bf16+oproj_bf16); alpha; mu; x2=LN(x1+bias2+mu@Wmix)
// ---------------------------------------------------------------------------
__global__ __launch_bounds__(256) void fused_mid(
    const u16* __restrict__ curb, const u16* __restrict__ oprojb,
    const float* __restrict__ g1, const float* __restrict__ b1,
    const float* __restrict__ Ut, const float* __restrict__ ab,
    const float* __restrict__ cvec,
    const float* __restrict__ Wmix, const float* __restrict__ bias2,
    const float* __restrict__ g2, const float* __restrict__ b2,
    __hip_bfloat16* __restrict__ x2b)
{
    const int w = threadIdx.x >> 6, lane = threadIdx.x & 63;
    const int row0 = blockIdx.x * 8 + w * 2;
    const int b = blockIdx.x >> 9;

    __shared__ float4 cvs[64];
    __shared__ float xp[4][64][28];
    __shared__ float muls[4][24];

    if (threadIdx.x < 64)
        cvs[threadIdx.x] = ((const float4*)(cvec + b * C_))[threadIdx.x];

    float4 x1[2][3];
#pragma unroll
    for (int rr = 0; rr < 2; ++rr) {
        const ushort4* pa = (const ushort4*)(curb + (size_t)(row0 + rr) * D_);
        const ushort4* pb = (const ushort4*)(oprojb + (size_t)(row0 + rr) * D_);
        float s = 0.f;
#pragma unroll
        for (int i = 0; i < 3; ++i) {
            ushort4 au = pa[i * 64 + lane];
            ushort4 ou = pb[i * 64 + lane];
            float4 v;
            v.x = bfu2f(au.x) + bfu2f(ou.x); v.y = bfu2f(au.y) + bfu2f(ou.y);
            v.z = bfu2f(au.z) + bfu2f(ou.z); v.w = bfu2f(au.w) + bfu2f(ou.w);
            x1[rr][i] = v;
            s += v.x + v.y + v.z + v.w;
        }
#pragma unroll
        for (int off = 1; off < 64; off <<= 1) s += __shfl_xor(s, off, 64);
        float mean = s * (1.0f / 768.0f);
        float sq = 0.f;
#pragma unroll
        for (int i = 0; i < 3; ++i) {
            x1[rr][i].x -= mean; x1[rr][i].y -= mean;
            x1[rr][i].z -= mean; x1[rr][i].w -= mean;
            sq += x1[rr][i].x * x1[rr][i].x + x1[rr][i].y * x1[rr][i].y
                + x1[rr][i].z * x1[rr][i].z + x1[rr][i].w * x1[rr][i].w;
        }
#pragma unroll
        for (int off = 1; off < 64; off <<= 1) sq += __shfl_xor(sq, off, 64);
        float rs = rsqrtf(sq * (1.0f / 768.0f) + 1e-5f);
#pragma unroll
        for (int i = 0; i < 3; ++i) {
            float4 gg = ((const float4*)g1)[i * 64 + lane];
            float4 bb = ((const float4*)b1)[i * 64 + lane];
            x1[rr][i].x = x1[rr][i].x * rs * gg.x + bb.x;
            x1[rr][i].y = x1[rr][i].y * rs * gg.y + bb.y;
            x1[rr][i].z = x1[rr][i].z * rs * gg.z + bb.z;
            x1[rr][i].w = x1[rr][i].w * rs * gg.w + bb.w;
        }
    }

    float acc[24];
#pragma unroll
    for (int j = 0; j < 24; ++j) acc[j] = 0.f;
#pragma unroll
    for (int i = 0; i < 3; ++i) {
#pragma unroll
        for (int h = 0; h < 12; ++h) {
            float4 u = ((const float4*)(Ut + (size_t)h * D_))[i * 64 + lane];
#pragma unroll
            for (int rr = 0; rr < 2; ++rr)
                acc[rr * 12 + h] += x1[rr][i].x * u.x + x1[rr][i].y * u.y
                                  + x1[rr][i].z * u.z + x1[rr][i].w * u.w;
        }
    }
#pragma unroll
    for (int j4 = 0; j4 < 6; ++j4)
        *(float4*)&xp[w][lane][j4 * 4] = *(float4*)&acc[j4 * 4];
    __syncthreads();

    if (lane < 48) {
        int j = lane >> 1, half = lane & 1;
        float ssum = 0.f;
#pragma unroll
        for (int k = 0; k < 32; ++k) ssum += xp[w][half * 32 + k][j];
        ssum += __shfl_xor(ssum, 1, 64);
        float a = 0.125f * (ssum + ab[j % 12]);
        float z = 0.f, ms = 0.f;
#pragma unroll
        for (int it = 0; it < 32; ++it) {
            float4 c = cvs[half * 32 + it];
            float e0 = __expf(a * c.x), e1 = __expf(a * c.y),
                  e2 = __expf(a * c.z), e3 = __expf(a * c.w);
            z += e0 + e1 + e2 + e3;
            ms += e0 * c.x + e1 * c.y + e2 * c.z + e3 * c.w;
        }
        z += __shfl_xor(z, 1, 64);
        ms += __shfl_xor(ms, 1, 64);
        if (half == 0) muls[w][j] = ms / z;
    }
    __syncthreads();

    float4 t2[2][3];
#pragma unroll
    for (int i = 0; i < 3; ++i) {
        float4 bv = ((const float4*)bias2)[i * 64 + lane];
        float4 o0 = bv, o1 = bv;
#pragma unroll
        for (int h = 0; h < 12; ++h) {
            float4 wm = ((const float4*)(Wmix + (size_t)h * D_))[i * 64 + lane];
            float m0 = muls[w][h], m1 = muls[w][12 + h];
            o0.x += m0 * wm.x; o0.y += m0 * wm.y; o0.z += m0 * wm.z; o0.w += m0 * wm.w;
            o1.x += m1 * wm.x; o1.y += m1 * wm.y; o1.z += m1 * wm.z; o1.w += m1 * wm.w;
        }
        t2[0][i].x = x1[0][i].x + o0.x; t2[0][i].y = x1[0][i].y + o0.y;
        t2[0][i].z = x1[0][i].z + o0.z; t2[0][i].w = x1[0][i].w + o0.w;
        t2[1][i].x = x1[1][i].x + o1.x; t2[1][i].y = x1[1][i].y + o1.y;
        t2[1][i].z = x1[1][i].z + o1.z; t2[1][i].w = x1[1][i].w + o1.w;
    }

#pragma unroll
    for (int rr = 0; rr < 2; ++rr) {
        float s = 0.f;
#pragma unroll
        for (int i = 0; i < 3; ++i)
            s += t2[rr][i].x + t2[rr][i].y + t2[rr][i].z + t2[rr][i].w;
#pragma unroll
        for (int off = 1; off < 64; off <<= 1) s += __shfl_xor(s, off, 64);
        float mean = s * (1.0f / 768.0f);
        float sq = 0.f;
#pragma unroll
        for (int i = 0; i < 3; ++i) {
            t2[rr][i].x -= mean; t2[rr][i].y -= mean;
            t2[rr][i].z -= mean; t2[rr][i].w -= mean;
            sq += t2[rr][i].x * t2[rr][i].x + t2[rr][i].y * t2[rr][i].y
                + t2[rr][i].z * t2[rr][i].z + t2[rr][i].w * t2[rr][i].w;
        }
#pragma unroll
        for (int off = 1; off < 64; off <<= 1) sq += __shfl_xor(sq, off, 64);
        float rs = rsqrtf(sq * (1.0f / 768.0f) + 1e-5f);
        size_t base = (size_t)(row0 + rr) * D_;
#pragma unroll
        for (int i = 0; i < 3; ++i) {
            float4 gg = ((const float4*)g2)[i * 64 + lane];
            float4 bb = ((const float4*)b2)[i * 64 + lane];
            float vx = t2[rr][i].x * rs * gg.x + bb.x;
            float vy = t2[rr][i].y * rs * gg.y + bb.y;
            float vz = t2[rr][i].z * rs * gg.z + bb.z;
            float vw = t2[rr][i].w * rs * gg.w + bb.w;
            __hip_bfloat16 pk[4] = {
                __float2bfloat16(vx), __float2bfloat16(vy),
                __float2bfloat16(vz), __float2bfloat16(vw)};
            *(uint2*)(x2b + base + i * 256 + lane * 4) = *(const uint2*)pk;
        }
    }
}

// ---------------------------------------------------------------------------
extern "C" void kernel_launch(void* const* d_in, const int* in_sizes, int n_in,
                              void* d_out, int out_size, void* d_ws, size_t ws_size,
                              hipStream_t stream) {
    const float* cur   = (const float*)d_in[0];
    const float* prev  = (const float*)d_in[1];
    const float* cvec  = (const float*)d_in[2];
    const int*   ridx  = (const int*)d_in[3];
    const float* Wq  = (const float*)d_in[4];
    const float* bq  = (const float*)d_in[5];
    const float* Wk  = (const float*)d_in[6];
    const float* bk  = (const float*)d_in[7];
    const float* Wv  = (const float*)d_in[8];
    const float* bv  = (const float*)d_in[9];
    const float* Wo  = (const float*)d_in[10];
    const float* bo  = (const float*)d_in[11];
    const float* g1  = (const float*)d_in[12];
    const float* b1  = (const float*)d_in[13];
    const float* Wqc = (const float*)d_in[14];
    const float* bqc = (const float*)d_in[15];
    const float* Wkc = (const float*)d_in[16];
    const float* bkc = (const float*)d_in[17];  (void)bkc;
    const float* Wvc = (const float*)d_in[18];
    const float* bvc = (const float*)d_in[19];
    const float* Woc = (const float*)d_in[20];
    const float* boc = (const float*)d_in[21];
    const float* g2  = (const float*)d_in[22];
    const float* b2  = (const float*)d_in[23];
    const float* W1  = (const float*)d_in[24];
    const float* bf1 = (const float*)d_in[25];
    const float* W2  = (const float*)d_in[26];
    const float* bf2 = (const float*)d_in[27];
    const float* g3  = (const float*)d_in[28];
    const float* b3  = (const float*)d_in[29];
    float* outp = (float*)d_out;
    (void)ws_size; (void)in_sizes; (void)n_in; (void)out_size;

    const int M = B_ * S_;                       // 16384
    const size_t NBSD = (size_t)M * D_;          // 12,582,912
    const size_t NSEL = (size_t)B_ * 128 * D_;   // 393,216

    __hip_bfloat16* hidb  = (__hip_bfloat16*)d_ws;          // M x FF (attn_out, then hid)
    __hip_bfloat16* bf0   = hidb + (size_t)M * FF_;         // cur_bf -> x2
    __hip_bfloat16* tmpb  = bf0 + NBSD;                     // q -> oproj -> ff
    __hip_bfloat16* Pselb = tmpb + NBSD;
    __hip_bfloat16* kvselb = Pselb + NSEL;                  // merged K|V, 512 x 1536
    __hip_bfloat16* Wqt   = kvselb + 2 * NSEL;
    __hip_bfloat16* Wot   = Wqt + (size_t)D_ * D_;
    __hip_bfloat16* Wkt   = Wot + (size_t)D_ * D_;          // Wkt||Wvt = [1536][768]
    __hip_bfloat16* Wvt   = Wkt + (size_t)D_ * D_;
    __hip_bfloat16* W1t   = Wvt + (size_t)D_ * D_;          // FF x D
    __hip_bfloat16* W2t   = W1t + (size_t)D_ * FF_;         // D x FF
    float* Ub    = (float*)(W2t + (size_t)FF_ * D_);
    float* abv   = Ub + (size_t)D_ * H_;
    float* Wmix  = abv + 16;
    float* bias2 = Wmix + (size_t)H_ * D_;
    int*   selb  = (int*)(bias2 + D_);
    float* bkv   = (float*)(selb + 512);                    // 1536 floats

    // 1) ALL independent prep in ONE dispatch
    preamble<<<PRE_NBLK, 256, 0, stream>>>(
        cur, prev, ridx, Wq, Wo, Wk, Wv, W1, W2,
        Wqc, Wkc, bqc, Wvc, Woc, bvc, boc, bk, bv,
        Pselb, selb, bf0, Wqt, Wot, Wkt, Wvt, W1t, W2t,
        Ub, abv, Wmix, bias2, bkv);

    // 2) q-proj + merged K|V-proj in ONE dispatch (816 blocks)
    gemm128_qkv<<<816, 512, 0, stream>>>(
        (const u16*)bf0, (const u16*)Wqt, bq, (u16*)tmpb,
        (const u16*)Pselb, (const u16*)Wkt, bkv, (u16*)kvselb);

    // 3) MFMA sparse attention -> hidb (cur_bf preserved in bf0)
    attn3_kernel<<<dim3(S_ / 256, B_ * H_), 256, 0, stream>>>(
        (const u16*)tmpb, (const u16*)kvselb, selb, (u16*)hidb);

    // 4) oproj = attn_out @ Wo + bo -> tmpb (q dead)
    gemm128<<<dim3(D_ / 128, M / 128), 512, 0, stream>>>(
        (const u16*)hidb, (const u16*)Wot, bo, (u16*)tmpb, M, D_, D_, 1);

    // 5) fused mid (r18): 2 rows/wave -> bf0 (in-place over cur_bf)
    fused_mid<<<M / 8, 256, 0, stream>>>(
        (const u16*)bf0, (const u16*)tmpb, g1, b1, Ub, abv, cvec, Wmix, bias2,
        g2, b2, bf0);

    // 6) FF via 8-phase 256^2: hid -> hidb (768 blocks); ff -> tmpb (192)
    gemm256<<<dim3(FF_ / 256, M / 256), 512, 0, stream>>>(
        (const u16*)bf0, (const u16*)W1t, bf1, (u16*)hidb, M, FF_, D_, 1 | 2);
    gemm256<<<dim3(D_ / 256, M / 256), 512, 0, stream>>>(
        (const u16*)hidb, (const u16*)W2t, bf2, (u16*)tmpb, M, D_, FF_, 1);

    // 7) out = LN(x2 + ff)
    addln_bb<<<M, 192, 0, stream>>>((const u16*)bf0, (const u16*)tmpb, g3, b3, outp);
}